// Round 2
// baseline (19988.736 us; speedup 1.0000x reference)
//
#include <hip/hip_runtime.h>
#include <cstdint>
#include <cstddef>

// ---------------------------------------------------------------------------
// StepWiseMLPAutoEncoder (MI355X/gfx950) — round 6: latency attack
//   r5 post-mortem: traffic cut 8x, time -12% -> decoder is LATENCY-bound,
//   not MALL-BW-bound (each CU sustains ~1 outstanding chain; my asm
//   "4 loads + vmcnt(0)" made 8 sequential ~1000cy MALL drains per phase).
//   Now:
//    (1) per-step h1/h2 slots in dead encoder memory -> ALL activation reads
//        are write-once-per-dispatch -> plain cached loads (L2-hit ~250cy,
//        32 CUs/XCD share each MALL fill). Same protocol as the passing
//        comb-slot cached reads.
//    (2) preload-all-then-consume: each wave issues its whole act slice
//        (33-34 float4, ~136 VGPR, static idx) before one wait;
//        sched_barrier(0) stops the compiler sinking loads to uses.
//    (3) all 256 wgs active every phase (tight arrival spread).
// ---------------------------------------------------------------------------

#define TT 256
#define BB 64
#define SS 1024

#define EK1 2049
#define EN1 944
#define EN2 416
#define EN3 32

#define DN1 1046
#define DN2 1035
#define DN3 1024

// K paddings (quad-multiples) and padded WT row counts
#define KP1 1060   // 32 ctrl + 1024 prev + 1 t + 3 pad
#define KP2 1048   // 1046 + 2
#define KP3 1036   // 1035 + 1
#define NQ1 265
#define NQ2 262
#define NQ3 259
#define WROWS1 1048
#define WROWS2 1040
#define WROWS3 1028

// ws layout (float offsets)
#define OFF_XT    ((size_t)0)                        // xt: 16,777,216 (dead after E1)
#define OFF_WT1   ((size_t)0)                        //  1048*1060 = 1,110,880
#define OFF_WT2   ((size_t)1110880)                  //  1040*1048 = 1,089,920
#define OFF_WT3   ((size_t)2200800)                  //  1028*1036 = 1,065,008 -> ends 3,265,808
#define OFF_H1S   ((size_t)3266048)                  // 256 slots x 67,072 = 17,170,432 -> ends 20,436,480
#define OFF_H2S   ((size_t)20436480)                 // 256 slots x 66,304 = 16,973,824 -> ends 37,410,304
#define OFF_E1    ((size_t)16777216)                 // encoder-time only (overwritten by h1s/h2s later)
#define OFF_E2    ((size_t)(OFF_E1 + 15466496))      // encoder-time only
#define OFF_COMB  ((size_t)(OFF_E2 + 6815744))       // 39,059,456: 257*265*256 = 17,434,880
#define OFF_BAR   ((size_t)(OFF_COMB + 17434880))    // 2048 words
// total ~226 MB (unchanged from r5)

#define COMB_SLOT (265 * 256)
#define H1_SLOT   (262 * 256)
#define H2_SLOT   (259 * 256)

// ---------------------------------------------------------------------------
__global__ void zero_init(float* __restrict__ p, size_t n) {
  size_t i = (size_t)blockIdx.x * blockDim.x + threadIdx.x;
  size_t stride = (size_t)gridDim.x * blockDim.x;
  for (; i < n; i += stride) p[i] = 0.f;
}

// x[b][s][t] -> xt[b][t][s]
__global__ void transpose_x(const float* __restrict__ x, float* __restrict__ xt) {
  __shared__ float tile[32][33];
  int b = blockIdx.z;
  int s0 = blockIdx.x << 5;
  int t0 = blockIdx.y << 5;
  int lt = threadIdx.x & 31;
  int ls = threadIdx.x >> 5;
  const float* xp = x + (size_t)b * SS * TT;
#pragma unroll
  for (int i = 0; i < 4; i++) {
    int s = s0 + ls + (i << 3);
    tile[ls + (i << 3)][lt] = xp[(size_t)s * TT + t0 + lt];
  }
  __syncthreads();
  float* xtp = xt + (size_t)b * TT * SS;
#pragma unroll
  for (int i = 0; i < 4; i++) {
    int t = t0 + ls + (i << 3);
    xtp[(size_t)t * SS + s0 + lt] = tile[lt][ls + (i << 3)];
  }
}

// W[k][n] -> WT[c][k], zero-padded to KPAD cols / NCP rows
__global__ void transpose_w(const float* __restrict__ W, float* __restrict__ WT,
                            int K, int N, int KPAD, int NCP) {
  __shared__ float tl[32][33];
  int c0 = blockIdx.x << 5, k0 = blockIdx.y << 5;
  int lx = threadIdx.x & 31, ly = threadIdx.x >> 5;  // 0..7
#pragma unroll
  for (int i = 0; i < 4; i++) {
    int k = k0 + ly + (i << 3);
    int c = c0 + lx;
    tl[ly + (i << 3)][lx] = (k < K && c < N) ? W[(size_t)k * N + c] : 0.f;
  }
  __syncthreads();
#pragma unroll
  for (int i = 0; i < 4; i++) {
    int c = c0 + ly + (i << 3);
    int k = k0 + lx;
    if (c < NCP && k < KPAD) WT[(size_t)c * KPAD + k] = tl[lx][ly + (i << 3)];
  }
}

// comb[t][quad 264][r][0] = t/256, [1..3] = 0
__global__ void init_tail(float* __restrict__ comb) {
  int i = blockIdx.x * blockDim.x + threadIdx.x;  // 0..16383
  int t = i >> 6, r = i & 63;
  float4 v;
  v.x = (float)t * (1.f / 256.f);
  v.y = v.z = v.w = 0.f;
  *(float4*)(comb + ((size_t)t * 265 + 264) * 256 + (r << 2)) = v;
}

// virtual A for encoder layer 1: row m=(b,t), k: [prev(1024) | cur(1024) | t | pad]
__device__ inline float4 e1_fetch(const float* __restrict__ xt, int m, int kg) {
  float4 z; z.x = z.y = z.z = z.w = 0.f;
  int t = m & 255;
  if (kg < 1024) {
    if (t == 0) return z;
    return *(const float4*)(xt + (((size_t)(m - 1)) << 10) + kg);
  } else if (kg < 2048) {
    return *(const float4*)(xt + (((size_t)m) << 10) + (kg - 1024));
  } else if (kg == 2048) {
    z.x = (float)t * (1.0f / 256.0f);
    return z;
  }
  return z;
}

// ---------------------------------------------------------------------------
// Tiled fp32 GEMM: C[M][N] = act(A[M][K] @ B[K][N] + bias). BM=128 BN=64 BK=16.
// SCATTER epilogue writes ctrl into comb prefix: comb[t][n>>2][b][n&3].
template <int AMODE, bool RELU, bool SCATTER>
__global__ __launch_bounds__(256, 2) void gemm_enc(
    const float* __restrict__ A, const float* __restrict__ Bw,
    const float* __restrict__ bias, float* __restrict__ C, int K, int N) {
  __shared__ float As[16][132];
  __shared__ float Bs[16][68];
  const int tid = threadIdx.x;
  const int m0 = blockIdx.x << 7;
  const int n0 = blockIdx.y << 6;
  const int rr = tid >> 4;
  const int cc = tid & 15;
  float acc[8][4];
#pragma unroll
  for (int i = 0; i < 8; i++)
#pragma unroll
    for (int j = 0; j < 4; j++) acc[i][j] = 0.f;

  const int ar = tid >> 2;
  const int akq = (tid & 3) << 2;
  const int bk = tid >> 4;
  const int bn = (tid & 15) << 2;

  for (int k0 = 0; k0 < K; k0 += 16) {
#pragma unroll
    for (int p = 0; p < 2; p++) {
      int m = m0 + ar + (p << 6);
      float4 v;
      if (AMODE == 1) v = e1_fetch(A, m, k0 + akq);
      else            v = *(const float4*)(A + (size_t)m * K + k0 + akq);
      As[akq + 0][ar + (p << 6)] = v.x;
      As[akq + 1][ar + (p << 6)] = v.y;
      As[akq + 2][ar + (p << 6)] = v.z;
      As[akq + 3][ar + (p << 6)] = v.w;
    }
    {
      float4 v; v.x = v.y = v.z = v.w = 0.f;
      if ((k0 + bk) < K && (n0 + bn) < N)
        v = *(const float4*)(Bw + (size_t)(k0 + bk) * N + n0 + bn);
      *(float4*)&Bs[bk][bn] = v;
    }
    __syncthreads();
#pragma unroll
    for (int kk = 0; kk < 16; kk++) {
      float a[8], b4[4];
      *(float4*)&a[0] = *(const float4*)&As[kk][rr << 3];
      *(float4*)&a[4] = *(const float4*)&As[kk][(rr << 3) + 4];
      *(float4*)&b4[0] = *(const float4*)&Bs[kk][cc << 2];
#pragma unroll
      for (int i = 0; i < 8; i++)
#pragma unroll
        for (int j = 0; j < 4; j++) acc[i][j] += a[i] * b4[j];
    }
    __syncthreads();
  }

  if (!SCATTER) {
#pragma unroll
    for (int i = 0; i < 8; i++) {
      int m = m0 + (rr << 3) + i;
      int n = n0 + (cc << 2);
      if (n + 3 < N) {
        float4 o;
        o.x = acc[i][0] + bias[n + 0];
        o.y = acc[i][1] + bias[n + 1];
        o.z = acc[i][2] + bias[n + 2];
        o.w = acc[i][3] + bias[n + 3];
        if (RELU) {
          o.x = fmaxf(o.x, 0.f); o.y = fmaxf(o.y, 0.f);
          o.z = fmaxf(o.z, 0.f); o.w = fmaxf(o.w, 0.f);
        }
        *(float4*)(C + (size_t)m * N + n) = o;
      } else {
#pragma unroll
        for (int j = 0; j < 4; j++) {
          if (n + j < N) {
            float v = acc[i][j] + bias[n + j];
            if (RELU) v = fmaxf(v, 0.f);
            C[(size_t)m * N + n + j] = v;
          }
        }
      }
    }
  } else {
    // ctrl -> comb prefix: m = b*256 + t; comb[t][n>>2][b][n&3]
#pragma unroll
    for (int i = 0; i < 8; i++) {
      int m = m0 + (rr << 3) + i;
      int t = m & 255, b = m >> 8;
#pragma unroll
      for (int j = 0; j < 4; j++) {
        int n = n0 + (cc << 2) + j;
        if (n < EN3)
          C[((size_t)t * 265 + (n >> 2)) * 256 + (b << 2) + (n & 3)] = acc[i][j] + bias[n];
      }
    }
  }
}

// ---------------------------------------------------------------------------
// Hierarchical fence-free global barrier (16 groups x 16 + root + 16 release
// lines, all agent-scope relaxed atomics at MALL). Producer data is at MALL
// before arrive: __syncthreads drains each wave's vmcnt; all mutable stores
// are sc0+sc1 (performed at MALL).
__device__ inline void gbar(unsigned* __restrict__ bar, unsigned gen, int w) {
  __syncthreads();
  if (threadIdx.x == 0) {
    asm volatile("s_waitcnt vmcnt(0)" ::: "memory");
    const int g = w & 15;
    unsigned old = __hip_atomic_fetch_add(bar + g * 32, 1u, __ATOMIC_RELAXED,
                                          __HIP_MEMORY_SCOPE_AGENT);
    bool released = false;
    if (old == (gen << 4) - 1u) {                 // last of my 16-wg group
      unsigned old2 = __hip_atomic_fetch_add(bar + 512, 1u, __ATOMIC_RELAXED,
                                             __HIP_MEMORY_SCOPE_AGENT);
      if (old2 == (gen << 4) - 1u) {              // last of the 16 groups
        released = true;
#pragma unroll
        for (int i = 0; i < 16; i++)
          __hip_atomic_store(bar + 544 + i * 32, gen, __ATOMIC_RELAXED,
                             __HIP_MEMORY_SCOPE_AGENT);
      }
    }
    if (!released) {
      unsigned* rel = bar + 544 + g * 32;
      while (__hip_atomic_load(rel, __ATOMIC_RELAXED, __HIP_MEMORY_SCOPE_AGENT) < gen)
        __builtin_amdgcn_s_sleep(2);
    }
  }
  __syncthreads();
}

// ---------------------------------------------------------------------------
// NCM weight float4s (plain cached; immutable, L1/L2-resident) vs one act quad.
#define DEC_FMA(av, jj)                                              \
  do {                                                               \
    const float* wq = w0 + ((jj) << 2);                              \
    _Pragma("unroll") for (int c = 0; c < NCM; c++) {                \
      float4 wv = *(const float4*)(wq + (size_t)c * KPAD);           \
      acc[c] = fmaf((av).x, wv.x, acc[c]);                           \
      acc[c] = fmaf((av).y, wv.y, acc[c]);                           \
      acc[c] = fmaf((av).z, wv.z, acc[c]);                           \
      acc[c] = fmaf((av).w, wv.w, acc[c]);                           \
    }                                                                \
  } while (0)

// One decoder layer phase, fully cached (all act buffers are write-once per
// dispatch -> no stale-L2 hazard; L2-hit after the XCD's first toucher).
// Preload-all-then-consume: issue the wave's whole act slice (DMAX float4,
// static indices -> registers), sched_barrier(0), then FMA. One latency
// exposure instead of DMAX/4 sequential drains.
template <int NQ, int KPAD, bool RELU, int NCM>
__device__ __forceinline__ void dec_phase(
    const float* __restrict__ actb, const float* __restrict__ wt,
    const float* __restrict__ bias, float* __restrict__ outb, int outk_off,
    int nc, int colbase, int r, int q, float* __restrict__ red, int tid) {
  constexpr int DMAX = (NQ + 7) / 8;  // 34 / 33 / 33
  const float* ab = actb + (r << 2);
  float4 av[DMAX];
#pragma unroll
  for (int i = 0; i < DMAX; i++) {
    int j = q + (i << 3);               // wave-uniform guard (q uniform)
    if (j < NQ) av[i] = *(const float4*)(ab + (j << 8));
    else { av[i].x = av[i].y = av[i].z = av[i].w = 0.f; }
  }
  __builtin_amdgcn_sched_barrier(0);    // keep all loads issued before use

  float acc[NCM];
#pragma unroll
  for (int c = 0; c < NCM; c++) acc[c] = 0.f;
  const float* w0 = wt + (size_t)colbase * KPAD;
#pragma unroll
  for (int i = 0; i < DMAX; i++) {
    int j = q + (i << 3);
    if (j < NQ) DEC_FMA(av[i], j);
  }

  // cross-q reduction via LDS (stride 9: only 2-way bank aliasing)
  float* rp = red + tid * 9;
#pragma unroll
  for (int c = 0; c < NCM; c++) rp[c] = acc[c];
  __syncthreads();
  if (tid < (nc << 6)) {
    int rr = tid / nc;
    int cc = tid - rr * nc;
    float s = 0.f;
#pragma unroll
    for (int q2 = 0; q2 < 8; q2++) s += red[((q2 << 6) + rr) * 9 + cc];
    s += bias[colbase + cc];
    if (RELU) s = fmaxf(s, 0.f);
    int kk = outk_off + colbase + cc;
    __hip_atomic_store(outb + ((size_t)(kk >> 2) << 8) + (rr << 2) + (kk & 3), s,
                       __ATOMIC_RELAXED, __HIP_MEMORY_SCOPE_AGENT);
  }
}

// Persistent decoder: 256 wgs x 512 thr, 3 barriers/step, all wgs active in
// every phase, all act reads cached (per-step write-once slots).
__global__ __launch_bounds__(512, 1) void decoder_kernel(
    const float* __restrict__ wt1, const float* __restrict__ b1,
    const float* __restrict__ wt2, const float* __restrict__ b2,
    const float* __restrict__ wt3, const float* __restrict__ b3,
    float* __restrict__ comb, float* __restrict__ h1s, float* __restrict__ h2s,
    unsigned* __restrict__ bar) {
  __shared__ float red[512 * 9];
  const int tid = threadIdx.x;
  const int w = blockIdx.x;
  const int r = tid & 63;
  const int q = __builtin_amdgcn_readfirstlane(tid >> 6);

  // L1: 22 wgs x 5 + 234 x 4 = 1046
  const int nc1 = (w < 22) ? 5 : 4;
  const int cb1 = (w < 22) ? w * 5 : 110 + (w - 22) * 4;
  // L2: 11 wgs x 5 + 245 x 4 = 1035
  const int nc2 = (w < 11) ? 5 : 4;
  const int cb2 = (w < 11) ? w * 5 : 55 + (w - 11) * 4;
  // L3: 256 x 4 = 1024
  const int cb3 = w << 2;

  unsigned gen = 0;
  for (int t = 0; t < TT; t++) {
    gen++; gbar(bar, gen, w);
    dec_phase<NQ1, KP1, true, 5>(comb + (size_t)t * COMB_SLOT, wt1, b1,
                                 h1s + (size_t)t * H1_SLOT, 0,
                                 nc1, cb1, r, q, red, tid);
    gen++; gbar(bar, gen, w);
    dec_phase<NQ2, KP2, true, 5>(h1s + (size_t)t * H1_SLOT, wt2, b2,
                                 h2s + (size_t)t * H2_SLOT, 0,
                                 nc2, cb2, r, q, red, tid);
    gen++; gbar(bar, gen, w);
    dec_phase<NQ3, KP3, false, 4>(h2s + (size_t)t * H2_SLOT, wt3, b3,
                                  comb + (size_t)(t + 1) * COMB_SLOT, 32,
                                  4, cb3, r, q, red, tid);
  }
}

// ---------------------------------------------------------------------------
// comb[t+1][8+Q][b][kk] -> out[b][4Q+kk][t]. grid (256 quads, 4 t-tiles), 256 thr.
__global__ void permute_out2(const float* __restrict__ comb, float* __restrict__ out) {
  __shared__ float tl[64 * 261];  // [r] stride 261, [kk] stride 65, [tt]
  int Q = blockIdx.x;
  int t0 = blockIdx.y << 6;
  int tid = threadIdx.x;
  int r = tid & 63, ts = tid >> 6;  // ts 0..3
#pragma unroll
  for (int i = 0; i < 16; i++) {
    int tt = (i << 2) + ts;
    float4 v = *(const float4*)(comb + ((size_t)(t0 + tt + 1) * 265 + 8 + Q) * 256 + (r << 2));
    float* p = &tl[r * 261];
    p[tt] = v.x; p[65 + tt] = v.y; p[130 + tt] = v.z; p[195 + tt] = v.w;
  }
  __syncthreads();
  int kk = tid & 3, r2 = tid >> 2;
  const float* p = &tl[r2 * 261 + kk * 65];
  float* o = out + ((size_t)r2 * 1024 + (Q << 2) + kk) * 256 + t0;
#pragma unroll
  for (int i = 0; i < 16; i++) {
    int b = i << 2;
    float4 v;
    v.x = p[b]; v.y = p[b + 1]; v.z = p[b + 2]; v.w = p[b + 3];
    *(float4*)(o + b) = v;
  }
}

// ---------------------------------------------------------------------------
extern "C" void kernel_launch(void* const* d_in, const int* in_sizes, int n_in,
                              void* d_out, int out_size, void* d_ws, size_t ws_size,
                              hipStream_t stream) {
  (void)in_sizes; (void)n_in; (void)out_size; (void)ws_size;
  const float* x   = (const float*)d_in[0];
  const float* eW1 = (const float*)d_in[1];
  const float* eb1 = (const float*)d_in[2];
  const float* eW2 = (const float*)d_in[3];
  const float* eb2 = (const float*)d_in[4];
  const float* eW3 = (const float*)d_in[5];
  const float* eb3 = (const float*)d_in[6];
  const float* dW1 = (const float*)d_in[7];
  const float* db1 = (const float*)d_in[8];
  const float* dW2 = (const float*)d_in[9];
  const float* db2 = (const float*)d_in[10];
  const float* dW3 = (const float*)d_in[11];
  const float* db3 = (const float*)d_in[12];

  float* ws    = (float*)d_ws;
  float* xt    = ws + OFF_XT;
  float* wt1p  = ws + OFF_WT1;
  float* wt2p  = ws + OFF_WT2;
  float* wt3p  = ws + OFF_WT3;
  float* h1sp  = ws + OFF_H1S;
  float* h2sp  = ws + OFF_H2S;
  float* e1p   = ws + OFF_E1;
  float* e2p   = ws + OFF_E2;
  float* combp = ws + OFF_COMB;
  unsigned* barp = (unsigned*)(ws + OFF_BAR);

  // zero comb slot 0 (t=0 "previous stft" = 0) and barrier region
  zero_init<<<dim3(64), dim3(256), 0, stream>>>(combp, (size_t)COMB_SLOT);
  zero_init<<<dim3(1), dim3(256), 0, stream>>>((float*)barp, (size_t)2048);

  transpose_x<<<dim3(32, 8, 64), dim3(256), 0, stream>>>(x, xt);

  // encoder (E1 consumes xt; xt/E1/E2 regions are reused for WT/h-slots after)
  gemm_enc<1, true,  false><<<dim3(128, 15), dim3(256), 0, stream>>>(xt,  eW1, eb1, e1p, EK1, EN1);
  gemm_enc<0, true,  false><<<dim3(128, 7),  dim3(256), 0, stream>>>(e1p, eW2, eb2, e2p, EN1, EN2);
  gemm_enc<0, false, true ><<<dim3(128, 1),  dim3(256), 0, stream>>>(e2p, eW3, eb3, combp, EN2, EN3);

  // decoder weight transposes (after E1 so xt region is dead)
  transpose_w<<<dim3(33, 34), dim3(256), 0, stream>>>(dW1, wt1p, 1057, DN1, KP1, WROWS1);
  transpose_w<<<dim3(33, 33), dim3(256), 0, stream>>>(dW2, wt2p, 1046, DN2, KP2, WROWS2);
  transpose_w<<<dim3(33, 33), dim3(256), 0, stream>>>(dW3, wt3p, 1035, DN3, KP3, WROWS3);
  init_tail<<<dim3(64), dim3(256), 0, stream>>>(combp);

  // persistent cooperative decoder
  const float *a0 = wt1p, *a1 = db1, *a2 = wt2p, *a3 = db2, *a4 = wt3p, *a5 = db3;
  float *r0 = combp, *r1 = h1sp, *r2 = h2sp;
  unsigned* r3 = barp;
  void* kargs[] = {&a0, &a1, &a2, &a3, &a4, &a5, &r0, &r1, &r2, &r3};
  hipLaunchCooperativeKernel((void*)decoder_kernel, dim3(256), dim3(512), kargs,
                             0, stream);

  permute_out2<<<dim3(256, 4), dim3(256), 0, stream>>>(combp, (float*)d_out);
}

// Round 3
// 8991.547 us; speedup vs baseline: 2.2231x; 2.2231x over previous
//
#include <hip/hip_runtime.h>
#include <cstdint>
#include <cstddef>

// ---------------------------------------------------------------------------
// StepWiseMLPAutoEncoder (MI355X/gfx950) — round 7: zero-RMW flag barrier
//   r5/r6 triangulation: per-phase time is dominated by same-line atomic RMW
//   serialization in the hierarchical barrier (~7-9 us/phase), not act BW and
//   not act latency. r6's preload also chunked (VGPR 100) adding VALU noise.
//   Now:
//    (1) barrier = 256 per-wg flag words; arrive is ONE plain agent store
//        (parallel, no ownership serialization); detect is wave-0 sweeping
//        all 256 flags with one dwordx4 sc0sc1 per lane + __all. No root,
//        no release, monotone gens.
//    (2) compute loop reverted to r5's simple cached float4 stride-8 loop
//        (VGPR ~32, compiler software-pipelines; acts are write-once
//        per-step slots -> plain cached loads, protocol proven in r6).
// ---------------------------------------------------------------------------

#define TT 256
#define BB 64
#define SS 1024

#define EK1 2049
#define EN1 944
#define EN2 416
#define EN3 32

#define DN1 1046
#define DN2 1035
#define DN3 1024

// K paddings (quad-multiples) and padded WT row counts
#define KP1 1060   // 32 ctrl + 1024 prev + 1 t + 3 pad
#define KP2 1048   // 1046 + 2
#define KP3 1036   // 1035 + 1
#define NQ1 265
#define NQ2 262
#define NQ3 259
#define WROWS1 1048
#define WROWS2 1040
#define WROWS3 1028

// ws layout (float offsets)
#define OFF_XT    ((size_t)0)                        // xt: 16,777,216 (dead after E1)
#define OFF_WT1   ((size_t)0)                        //  1048*1060 = 1,110,880
#define OFF_WT2   ((size_t)1110880)                  //  1040*1048 = 1,089,920
#define OFF_WT3   ((size_t)2200800)                  //  1028*1036 = 1,065,008 -> ends 3,265,808
#define OFF_H1S   ((size_t)3266048)                  // 256 slots x 67,072 -> ends 20,436,480
#define OFF_H2S   ((size_t)20436480)                 // 256 slots x 66,304 -> ends 37,410,304
#define OFF_E1    ((size_t)16777216)                 // encoder-time only (reused by h-slots)
#define OFF_E2    ((size_t)(OFF_E1 + 15466496))      // encoder-time only
#define OFF_COMB  ((size_t)(OFF_E2 + 6815744))       // 39,059,456: 257*265*256
#define OFF_BAR   ((size_t)(OFF_COMB + 17434880))    // 256 flag words (+pad)
// total ~226 MB

#define COMB_SLOT (265 * 256)
#define H1_SLOT   (262 * 256)
#define H2_SLOT   (259 * 256)

typedef unsigned uint4v __attribute__((ext_vector_type(4)));

// ---------------------------------------------------------------------------
__global__ void zero_init(float* __restrict__ p, size_t n) {
  size_t i = (size_t)blockIdx.x * blockDim.x + threadIdx.x;
  size_t stride = (size_t)gridDim.x * blockDim.x;
  for (; i < n; i += stride) p[i] = 0.f;
}

// x[b][s][t] -> xt[b][t][s]
__global__ void transpose_x(const float* __restrict__ x, float* __restrict__ xt) {
  __shared__ float tile[32][33];
  int b = blockIdx.z;
  int s0 = blockIdx.x << 5;
  int t0 = blockIdx.y << 5;
  int lt = threadIdx.x & 31;
  int ls = threadIdx.x >> 5;
  const float* xp = x + (size_t)b * SS * TT;
#pragma unroll
  for (int i = 0; i < 4; i++) {
    int s = s0 + ls + (i << 3);
    tile[ls + (i << 3)][lt] = xp[(size_t)s * TT + t0 + lt];
  }
  __syncthreads();
  float* xtp = xt + (size_t)b * TT * SS;
#pragma unroll
  for (int i = 0; i < 4; i++) {
    int t = t0 + ls + (i << 3);
    xtp[(size_t)t * SS + s0 + lt] = tile[lt][ls + (i << 3)];
  }
}

// W[k][n] -> WT[c][k], zero-padded to KPAD cols / NCP rows
__global__ void transpose_w(const float* __restrict__ W, float* __restrict__ WT,
                            int K, int N, int KPAD, int NCP) {
  __shared__ float tl[32][33];
  int c0 = blockIdx.x << 5, k0 = blockIdx.y << 5;
  int lx = threadIdx.x & 31, ly = threadIdx.x >> 5;  // 0..7
#pragma unroll
  for (int i = 0; i < 4; i++) {
    int k = k0 + ly + (i << 3);
    int c = c0 + lx;
    tl[ly + (i << 3)][lx] = (k < K && c < N) ? W[(size_t)k * N + c] : 0.f;
  }
  __syncthreads();
#pragma unroll
  for (int i = 0; i < 4; i++) {
    int c = c0 + ly + (i << 3);
    int k = k0 + lx;
    if (c < NCP && k < KPAD) WT[(size_t)c * KPAD + k] = tl[lx][ly + (i << 3)];
  }
}

// comb[t][quad 264][r][0] = t/256, [1..3] = 0
__global__ void init_tail(float* __restrict__ comb) {
  int i = blockIdx.x * blockDim.x + threadIdx.x;  // 0..16383
  int t = i >> 6, r = i & 63;
  float4 v;
  v.x = (float)t * (1.f / 256.f);
  v.y = v.z = v.w = 0.f;
  *(float4*)(comb + ((size_t)t * 265 + 264) * 256 + (r << 2)) = v;
}

// virtual A for encoder layer 1: row m=(b,t), k: [prev(1024) | cur(1024) | t | pad]
__device__ inline float4 e1_fetch(const float* __restrict__ xt, int m, int kg) {
  float4 z; z.x = z.y = z.z = z.w = 0.f;
  int t = m & 255;
  if (kg < 1024) {
    if (t == 0) return z;
    return *(const float4*)(xt + (((size_t)(m - 1)) << 10) + kg);
  } else if (kg < 2048) {
    return *(const float4*)(xt + (((size_t)m) << 10) + (kg - 1024));
  } else if (kg == 2048) {
    z.x = (float)t * (1.0f / 256.0f);
    return z;
  }
  return z;
}

// ---------------------------------------------------------------------------
// Tiled fp32 GEMM: C[M][N] = act(A[M][K] @ B[K][N] + bias). BM=128 BN=64 BK=16.
// SCATTER epilogue writes ctrl into comb prefix: comb[t][n>>2][b][n&3].
template <int AMODE, bool RELU, bool SCATTER>
__global__ __launch_bounds__(256, 2) void gemm_enc(
    const float* __restrict__ A, const float* __restrict__ Bw,
    const float* __restrict__ bias, float* __restrict__ C, int K, int N) {
  __shared__ float As[16][132];
  __shared__ float Bs[16][68];
  const int tid = threadIdx.x;
  const int m0 = blockIdx.x << 7;
  const int n0 = blockIdx.y << 6;
  const int rr = tid >> 4;
  const int cc = tid & 15;
  float acc[8][4];
#pragma unroll
  for (int i = 0; i < 8; i++)
#pragma unroll
    for (int j = 0; j < 4; j++) acc[i][j] = 0.f;

  const int ar = tid >> 2;
  const int akq = (tid & 3) << 2;
  const int bk = tid >> 4;
  const int bn = (tid & 15) << 2;

  for (int k0 = 0; k0 < K; k0 += 16) {
#pragma unroll
    for (int p = 0; p < 2; p++) {
      int m = m0 + ar + (p << 6);
      float4 v;
      if (AMODE == 1) v = e1_fetch(A, m, k0 + akq);
      else            v = *(const float4*)(A + (size_t)m * K + k0 + akq);
      As[akq + 0][ar + (p << 6)] = v.x;
      As[akq + 1][ar + (p << 6)] = v.y;
      As[akq + 2][ar + (p << 6)] = v.z;
      As[akq + 3][ar + (p << 6)] = v.w;
    }
    {
      float4 v; v.x = v.y = v.z = v.w = 0.f;
      if ((k0 + bk) < K && (n0 + bn) < N)
        v = *(const float4*)(Bw + (size_t)(k0 + bk) * N + n0 + bn);
      *(float4*)&Bs[bk][bn] = v;
    }
    __syncthreads();
#pragma unroll
    for (int kk = 0; kk < 16; kk++) {
      float a[8], b4[4];
      *(float4*)&a[0] = *(const float4*)&As[kk][rr << 3];
      *(float4*)&a[4] = *(const float4*)&As[kk][(rr << 3) + 4];
      *(float4*)&b4[0] = *(const float4*)&Bs[kk][cc << 2];
#pragma unroll
      for (int i = 0; i < 8; i++)
#pragma unroll
        for (int j = 0; j < 4; j++) acc[i][j] += a[i] * b4[j];
    }
    __syncthreads();
  }

  if (!SCATTER) {
#pragma unroll
    for (int i = 0; i < 8; i++) {
      int m = m0 + (rr << 3) + i;
      int n = n0 + (cc << 2);
      if (n + 3 < N) {
        float4 o;
        o.x = acc[i][0] + bias[n + 0];
        o.y = acc[i][1] + bias[n + 1];
        o.z = acc[i][2] + bias[n + 2];
        o.w = acc[i][3] + bias[n + 3];
        if (RELU) {
          o.x = fmaxf(o.x, 0.f); o.y = fmaxf(o.y, 0.f);
          o.z = fmaxf(o.z, 0.f); o.w = fmaxf(o.w, 0.f);
        }
        *(float4*)(C + (size_t)m * N + n) = o;
      } else {
#pragma unroll
        for (int j = 0; j < 4; j++) {
          if (n + j < N) {
            float v = acc[i][j] + bias[n + j];
            if (RELU) v = fmaxf(v, 0.f);
            C[(size_t)m * N + n + j] = v;
          }
        }
      }
    }
  } else {
    // ctrl -> comb prefix: m = b*256 + t; comb[t][n>>2][b][n&3]
#pragma unroll
    for (int i = 0; i < 8; i++) {
      int m = m0 + (rr << 3) + i;
      int t = m & 255, b = m >> 8;
#pragma unroll
      for (int j = 0; j < 4; j++) {
        int n = n0 + (cc << 2) + j;
        if (n < EN3)
          C[((size_t)t * 265 + (n >> 2)) * 256 + (b << 2) + (n & 3)] = acc[i][j] + bias[n];
      }
    }
  }
}

// ---------------------------------------------------------------------------
// Zero-RMW flag barrier. bar[w] (w=0..255) is wg w's monotone generation flag.
// Arrive: one plain agent-scope store (parallel across wgs, no RMW ownership
// serialization). Detect: wave 0 sweeps all 256 flags — one dwordx4 sc0sc1
// per lane (64 lanes x 4 flags), __all(>= gen). No root, no release hop.
// Producer data visibility: __syncthreads drains every wave's vmcnt (stores
// acked at MALL, all mutable stores are agent-scope sc0sc1) BEFORE the flag
// store issues; flag and data share the coherence point -> flag visible =>
// data visible. Self-store may not be seen on first sweep (no wait between
// own store and load) — monotone retry heals.
__device__ inline void gbar(unsigned* __restrict__ bar, unsigned gen, int w) {
  __syncthreads();
  if (threadIdx.x == 0)
    __hip_atomic_store(bar + w, gen, __ATOMIC_RELAXED, __HIP_MEMORY_SCOPE_AGENT);
  if (threadIdx.x < 64) {
    const unsigned* fp = bar + (threadIdx.x << 2);
    for (;;) {
      uint4v f;
      asm volatile(
          "global_load_dwordx4 %0, %1, off sc0 sc1\n\t"
          "s_waitcnt vmcnt(0)"
          : "=v"(f) : "v"(fp));
      if (__all(f.x >= gen && f.y >= gen && f.z >= gen && f.w >= gen)) break;
      __builtin_amdgcn_s_sleep(1);
    }
  }
  __syncthreads();
}

// ---------------------------------------------------------------------------
// NCM weight float4s (plain cached; immutable, L1/L2-resident) vs one act quad.
#define DEC_FMA(av, jj)                                              \
  do {                                                               \
    const float* wq = w0 + ((jj) << 2);                              \
    _Pragma("unroll") for (int c = 0; c < NCM; c++) {                \
      float4 wv = *(const float4*)(wq + (size_t)c * KPAD);           \
      acc[c] = fmaf((av).x, wv.x, acc[c]);                           \
      acc[c] = fmaf((av).y, wv.y, acc[c]);                           \
      acc[c] = fmaf((av).z, wv.z, acc[c]);                           \
      acc[c] = fmaf((av).w, wv.w, acc[c]);                           \
    }                                                                \
  } while (0)

// One decoder layer phase, fully cached (act buffers are write-once per-step
// slots -> no stale-L2 hazard; first toucher per XCD fills L2, rest hit).
// Simple stride-8 loop (r5 structure): compiler software-pipelines 4 deep,
// 8 waves/CU overlap the rest.
template <int NQ, int KPAD, bool RELU, int NCM>
__device__ __forceinline__ void dec_phase(
    const float* __restrict__ actb, const float* __restrict__ wt,
    const float* __restrict__ bias, float* __restrict__ outb, int outk_off,
    int nc, int colbase, int r, int q, float* __restrict__ red, int tid) {
  float acc[NCM];
#pragma unroll
  for (int c = 0; c < NCM; c++) acc[c] = 0.f;
  const float* w0 = wt + (size_t)colbase * KPAD;
  const float* ab = actb + (r << 2);
#pragma unroll 4
  for (int j = q; j < NQ; j += 8) {
    float4 a = *(const float4*)(ab + (j << 8));
    DEC_FMA(a, j);
  }

  // cross-q reduction via LDS (stride 9: 2-way bank aliasing only)
  float* rp = red + tid * 9;
#pragma unroll
  for (int c = 0; c < NCM; c++) rp[c] = acc[c];
  __syncthreads();
  if (tid < (nc << 6)) {
    int rr = tid / nc;
    int cc = tid - rr * nc;
    float s = 0.f;
#pragma unroll
    for (int q2 = 0; q2 < 8; q2++) s += red[((q2 << 6) + rr) * 9 + cc];
    s += bias[colbase + cc];
    if (RELU) s = fmaxf(s, 0.f);
    int kk = outk_off + colbase + cc;
    __hip_atomic_store(outb + ((size_t)(kk >> 2) << 8) + (rr << 2) + (kk & 3), s,
                       __ATOMIC_RELAXED, __HIP_MEMORY_SCOPE_AGENT);
  }
}

// Persistent decoder: 256 wgs x 512 thr, 3 flag-barriers/step, all wgs active
// every phase, all act reads plain cached (per-step write-once slots).
__global__ __launch_bounds__(512, 1) void decoder_kernel(
    const float* __restrict__ wt1, const float* __restrict__ b1,
    const float* __restrict__ wt2, const float* __restrict__ b2,
    const float* __restrict__ wt3, const float* __restrict__ b3,
    float* __restrict__ comb, float* __restrict__ h1s, float* __restrict__ h2s,
    unsigned* __restrict__ bar) {
  __shared__ float red[512 * 9];
  const int tid = threadIdx.x;
  const int w = blockIdx.x;
  const int r = tid & 63;
  const int q = __builtin_amdgcn_readfirstlane(tid >> 6);

  // L1: 22 wgs x 5 + 234 x 4 = 1046
  const int nc1 = (w < 22) ? 5 : 4;
  const int cb1 = (w < 22) ? w * 5 : 110 + (w - 22) * 4;
  // L2: 11 wgs x 5 + 245 x 4 = 1035
  const int nc2 = (w < 11) ? 5 : 4;
  const int cb2 = (w < 11) ? w * 5 : 55 + (w - 11) * 4;
  // L3: 256 x 4 = 1024
  const int cb3 = w << 2;

  unsigned gen = 0;
  for (int t = 0; t < TT; t++) {
    gen++; gbar(bar, gen, w);
    dec_phase<NQ1, KP1, true, 5>(comb + (size_t)t * COMB_SLOT, wt1, b1,
                                 h1s + (size_t)t * H1_SLOT, 0,
                                 nc1, cb1, r, q, red, tid);
    gen++; gbar(bar, gen, w);
    dec_phase<NQ2, KP2, true, 5>(h1s + (size_t)t * H1_SLOT, wt2, b2,
                                 h2s + (size_t)t * H2_SLOT, 0,
                                 nc2, cb2, r, q, red, tid);
    gen++; gbar(bar, gen, w);
    dec_phase<NQ3, KP3, false, 4>(h2s + (size_t)t * H2_SLOT, wt3, b3,
                                  comb + (size_t)(t + 1) * COMB_SLOT, 32,
                                  4, cb3, r, q, red, tid);
  }
}

// ---------------------------------------------------------------------------
// comb[t+1][8+Q][b][kk] -> out[b][4Q+kk][t]. grid (256 quads, 4 t-tiles), 256 thr.
__global__ void permute_out2(const float* __restrict__ comb, float* __restrict__ out) {
  __shared__ float tl[64 * 261];  // [r] stride 261, [kk] stride 65, [tt]
  int Q = blockIdx.x;
  int t0 = blockIdx.y << 6;
  int tid = threadIdx.x;
  int r = tid & 63, ts = tid >> 6;  // ts 0..3
#pragma unroll
  for (int i = 0; i < 16; i++) {
    int tt = (i << 2) + ts;
    float4 v = *(const float4*)(comb + ((size_t)(t0 + tt + 1) * 265 + 8 + Q) * 256 + (r << 2));
    float* p = &tl[r * 261];
    p[tt] = v.x; p[65 + tt] = v.y; p[130 + tt] = v.z; p[195 + tt] = v.w;
  }
  __syncthreads();
  int kk = tid & 3, r2 = tid >> 2;
  const float* p = &tl[r2 * 261 + kk * 65];
  float* o = out + ((size_t)r2 * 1024 + (Q << 2) + kk) * 256 + t0;
#pragma unroll
  for (int i = 0; i < 16; i++) {
    int b = i << 2;
    float4 v;
    v.x = p[b]; v.y = p[b + 1]; v.z = p[b + 2]; v.w = p[b + 3];
    *(float4*)(o + b) = v;
  }
}

// ---------------------------------------------------------------------------
extern "C" void kernel_launch(void* const* d_in, const int* in_sizes, int n_in,
                              void* d_out, int out_size, void* d_ws, size_t ws_size,
                              hipStream_t stream) {
  (void)in_sizes; (void)n_in; (void)out_size; (void)ws_size;
  const float* x   = (const float*)d_in[0];
  const float* eW1 = (const float*)d_in[1];
  const float* eb1 = (const float*)d_in[2];
  const float* eW2 = (const float*)d_in[3];
  const float* eb2 = (const float*)d_in[4];
  const float* eW3 = (const float*)d_in[5];
  const float* eb3 = (const float*)d_in[6];
  const float* dW1 = (const float*)d_in[7];
  const float* db1 = (const float*)d_in[8];
  const float* dW2 = (const float*)d_in[9];
  const float* db2 = (const float*)d_in[10];
  const float* dW3 = (const float*)d_in[11];
  const float* db3 = (const float*)d_in[12];

  float* ws    = (float*)d_ws;
  float* xt    = ws + OFF_XT;
  float* wt1p  = ws + OFF_WT1;
  float* wt2p  = ws + OFF_WT2;
  float* wt3p  = ws + OFF_WT3;
  float* h1sp  = ws + OFF_H1S;
  float* h2sp  = ws + OFF_H2S;
  float* e1p   = ws + OFF_E1;
  float* e2p   = ws + OFF_E2;
  float* combp = ws + OFF_COMB;
  unsigned* barp = (unsigned*)(ws + OFF_BAR);

  // zero comb slot 0 (t=0 "previous stft" = 0) and barrier flags
  zero_init<<<dim3(64), dim3(256), 0, stream>>>(combp, (size_t)COMB_SLOT);
  zero_init<<<dim3(1), dim3(256), 0, stream>>>((float*)barp, (size_t)2048);

  transpose_x<<<dim3(32, 8, 64), dim3(256), 0, stream>>>(x, xt);

  // encoder (E1 consumes xt; xt/E1/E2 regions are reused for WT/h-slots after)
  gemm_enc<1, true,  false><<<dim3(128, 15), dim3(256), 0, stream>>>(xt,  eW1, eb1, e1p, EK1, EN1);
  gemm_enc<0, true,  false><<<dim3(128, 7),  dim3(256), 0, stream>>>(e1p, eW2, eb2, e2p, EN1, EN2);
  gemm_enc<0, false, true ><<<dim3(128, 1),  dim3(256), 0, stream>>>(e2p, eW3, eb3, combp, EN2, EN3);

  // decoder weight transposes (after E1 so xt region is dead)
  transpose_w<<<dim3(33, 34), dim3(256), 0, stream>>>(dW1, wt1p, 1057, DN1, KP1, WROWS1);
  transpose_w<<<dim3(33, 33), dim3(256), 0, stream>>>(dW2, wt2p, 1046, DN2, KP2, WROWS2);
  transpose_w<<<dim3(33, 33), dim3(256), 0, stream>>>(dW3, wt3p, 1035, DN3, KP3, WROWS3);
  init_tail<<<dim3(64), dim3(256), 0, stream>>>(combp);

  // persistent cooperative decoder
  const float *a0 = wt1p, *a1 = db1, *a2 = wt2p, *a3 = db2, *a4 = wt3p, *a5 = db3;
  float *r0 = combp, *r1 = h1sp, *r2 = h2sp;
  unsigned* r3 = barp;
  void* kargs[] = {&a0, &a1, &a2, &a3, &a4, &a5, &r0, &r1, &r2, &r3};
  hipLaunchCooperativeKernel((void*)decoder_kernel, dim3(256), dim3(512), kargs,
                             0, stream);

  permute_out2<<<dim3(256, 4), dim3(256), 0, stream>>>(combp, (float*)d_out);
}